// Round 1
// baseline (884.084 us; speedup 1.0000x reference)
//
#include <hip/hip_runtime.h>

typedef unsigned short u16;
typedef __attribute__((ext_vector_type(8))) __bf16 bf16x8;
typedef __attribute__((ext_vector_type(8))) short short8;
typedef __attribute__((ext_vector_type(4))) float f32x4;

#define NE 8            // experts
#define LDA 40          // LDS row stride in bf16 elems (80B, 16B-aligned, 20-bank stride)

__device__ __forceinline__ u16 f2bf(float f) {
    union { float f; unsigned u; } v; v.f = f;
    unsigned u = v.u;
    return (u16)((u + 0x7fffu + ((u >> 16) & 1u)) >> 16);
}

__device__ __forceinline__ f32x4 mfma16(short8 a, short8 b, f32x4 c) {
    return __builtin_amdgcn_mfma_f32_16x16x32_bf16(
        __builtin_bit_cast(bf16x8, a), __builtin_bit_cast(bf16x8, b), c, 0, 0, 0);
}

// ---------------- fp32 -> bf16 conversion (grid-stride, float4) ----------------
__global__ void cvt_kernel(const float* __restrict__ in, u16* __restrict__ out, size_t n4) {
    size_t i = (size_t)blockIdx.x * blockDim.x + threadIdx.x;
    size_t stride = (size_t)gridDim.x * blockDim.x;
    for (; i < n4; i += stride) {
        float4 v = ((const float4*)in)[i];
        ushort4 o;
        o.x = f2bf(v.x); o.y = f2bf(v.y); o.z = f2bf(v.z); o.w = f2bf(v.w);
        ((ushort4*)out)[i] = o;
    }
}

// ---------------- router: noisy top-2 gating, one wave per token ----------------
__global__ void router_kernel(const float* __restrict__ x, const float* __restrict__ noise,
                              const float* __restrict__ rw, const float* __restrict__ rb,
                              const float* __restrict__ nw, const float* __restrict__ nb,
                              int* __restrict__ counts, int* __restrict__ list,
                              float* __restrict__ glist, int T, int D) {
    int wv = threadIdx.x >> 6;
    int lane = threadIdx.x & 63;
    int t = blockIdx.x * 4 + wv;
    if (t >= T) return;

    // D == 1024: each lane owns 16 contiguous elems (4 float4)
    const float4* x4 = (const float4*)(x + (size_t)t * D) + lane * 4;
    float4 xv0 = x4[0], xv1 = x4[1], xv2 = x4[2], xv3 = x4[3];

    float lg[NE], nl[NE];
#pragma unroll
    for (int e = 0; e < NE; e++) {
        const float4* w4 = (const float4*)(rw + (size_t)e * D) + lane * 4;
        float4 a = w4[0], b = w4[1], c = w4[2], d = w4[3];
        float s = xv0.x*a.x + xv0.y*a.y + xv0.z*a.z + xv0.w*a.w
                + xv1.x*b.x + xv1.y*b.y + xv1.z*b.z + xv1.w*b.w
                + xv2.x*c.x + xv2.y*c.y + xv2.z*c.z + xv2.w*c.w
                + xv3.x*d.x + xv3.y*d.y + xv3.z*d.z + xv3.w*d.w;
#pragma unroll
        for (int m = 1; m < 64; m <<= 1) s += __shfl_xor(s, m);
        lg[e] = s + rb[e];

        const float4* v4 = (const float4*)(nw + (size_t)e * D) + lane * 4;
        a = v4[0]; b = v4[1]; c = v4[2]; d = v4[3];
        float s2 = xv0.x*a.x + xv0.y*a.y + xv0.z*a.z + xv0.w*a.w
                 + xv1.x*b.x + xv1.y*b.y + xv1.z*b.z + xv1.w*b.w
                 + xv2.x*c.x + xv2.y*c.y + xv2.z*c.z + xv2.w*c.w
                 + xv3.x*d.x + xv3.y*d.y + xv3.z*d.z + xv3.w*d.w;
#pragma unroll
        for (int m = 1; m < 64; m <<= 1) s2 += __shfl_xor(s2, m);
        nl[e] = s2 + nb[e];
    }

    if (lane == 0) {
        float v0 = -1e30f, v1 = -1e30f;
        int i0 = 0, i1 = 0;
#pragma unroll
        for (int e = 0; e < NE; e++) {
            float z = nl[e];
            float sp = (z > 20.f) ? z : log1pf(expf(z));
            float nv = lg[e] + noise[(size_t)t * NE + e] * sp;
            if (nv > v0) { v1 = v0; i1 = i0; v0 = nv; i0 = e; }
            else if (nv > v1) { v1 = nv; i1 = e; }
        }
        float e1 = expf(v1 - v0);
        float inv = 1.f / (1.f + e1);
        float g0 = inv, g1 = e1 * inv;
        int p0 = atomicAdd(&counts[i0], 1);
        list[i0 * T + p0] = t; glist[i0 * T + p0] = g0;
        int p1 = atomicAdd(&counts[i1], 1);
        list[i1 * T + p1] = t; glist[i1 * T + p1] = g1;
    }
}

// ---------------- tiny exclusive scan over 8 counts ----------------
__global__ void scan_kernel(const int* __restrict__ counts, int* __restrict__ offsets) {
    if (threadIdx.x == 0 && blockIdx.x == 0) {
        int s = 0;
        for (int e = 0; e < NE; e++) { offsets[e] = s; s += counts[e]; }
        offsets[NE] = s;
    }
}

// ---------------- GEMM1: h = silu(x@w1^T) * (x@w3^T) * gate  (gathered rows) ----------------
// tile: 128 rows x 64 cols-of-H, both w1 and w3. 4 waves, each 64x32 per matrix.
__launch_bounds__(256)
__global__ void gemm1_kernel(const u16* __restrict__ xb, const u16* __restrict__ w1b,
                             const u16* __restrict__ w3b,
                             const int* __restrict__ counts, const int* __restrict__ offsets,
                             const int* __restrict__ list, const float* __restrict__ glist,
                             u16* __restrict__ hb, int T, int D, int H) {
    int e = blockIdx.z, mblk = blockIdx.y, nblk = blockIdx.x;
    int count = counts[e];
    if (mblk * 128 >= count) return;

    __shared__ u16 sA[128 * LDA];
    __shared__ u16 sB1[64 * LDA];
    __shared__ u16 sB3[64 * LDA];
    __shared__ int stok[128];

    int tid = threadIdx.x;
    if (tid < 128) {
        int r = mblk * 128 + tid;
        stok[tid] = list[e * T + min(r, count - 1)];
    }
    __syncthreads();

    int n0 = nblk * 64;
    const u16* w1p = w1b + ((size_t)e * H + n0) * D;
    const u16* w3p = w3b + ((size_t)e * H + n0) * D;

    f32x4 acc1[4][2], acc3[4][2];
#pragma unroll
    for (int mi = 0; mi < 4; mi++)
#pragma unroll
        for (int ni = 0; ni < 2; ni++) { acc1[mi][ni] = (f32x4)0.f; acc3[mi][ni] = (f32x4)0.f; }

    int lane = tid & 63, wvi = tid >> 6;
    int wm = (wvi & 1) * 64, wn = (wvi >> 1) * 32;
    int r = lane & 15, q = lane >> 4;

    for (int k0 = 0; k0 < D; k0 += 32) {
        // stage A: 128 rows x 32 k (2 chunks of 16B per thread)
#pragma unroll
        for (int c = 0; c < 2; c++) {
            int idx = tid + c * 256;
            int row = idx >> 2;
            int col8 = (idx & 3) * 8;
            int tok = stok[row];
            *(uint4*)(&sA[row * LDA + col8]) =
                *(const uint4*)(xb + (size_t)tok * D + k0 + col8);
        }
        // stage B1/B3: 64 rows x 32 k each (1 chunk per thread each)
        {
            int row = tid >> 2;
            int col8 = (tid & 3) * 8;
            *(uint4*)(&sB1[row * LDA + col8]) =
                *(const uint4*)(w1p + (size_t)row * D + k0 + col8);
            *(uint4*)(&sB3[row * LDA + col8]) =
                *(const uint4*)(w3p + (size_t)row * D + k0 + col8);
        }
        __syncthreads();

        short8 a[4], b1[2], b3[2];
#pragma unroll
        for (int mi = 0; mi < 4; mi++)
            a[mi] = *(const short8*)(&sA[(wm + mi * 16 + r) * LDA + q * 8]);
#pragma unroll
        for (int ni = 0; ni < 2; ni++) {
            b1[ni] = *(const short8*)(&sB1[(wn + ni * 16 + r) * LDA + q * 8]);
            b3[ni] = *(const short8*)(&sB3[(wn + ni * 16 + r) * LDA + q * 8]);
        }
#pragma unroll
        for (int mi = 0; mi < 4; mi++)
#pragma unroll
            for (int ni = 0; ni < 2; ni++) {
                acc1[mi][ni] = mfma16(a[mi], b1[ni], acc1[mi][ni]);
                acc3[mi][ni] = mfma16(a[mi], b3[ni], acc3[mi][ni]);
            }
        __syncthreads();
    }

    // epilogue: silu(acc1)*acc3*gate -> bf16 h (packed rows at offsets[e])
    int hrow0 = offsets[e];
#pragma unroll
    for (int mi = 0; mi < 4; mi++) {
#pragma unroll
        for (int ni = 0; ni < 2; ni++) {
#pragma unroll
            for (int tt = 0; tt < 4; tt++) {
                int rl = wm + mi * 16 + q * 4 + tt;
                int grow = mblk * 128 + rl;
                if (grow < count) {
                    float g = glist[e * T + grow];
                    float av = acc1[mi][ni][tt];
                    float bv = acc3[mi][ni][tt];
                    float hv = av / (1.f + expf(-av)) * bv * g;
                    int col = n0 + wn + ni * 16 + r;
                    hb[(size_t)(hrow0 + grow) * H + col] = f2bf(hv);
                }
            }
        }
    }
}

// ---------------- GEMM2: out[token] += h @ w2^T (gate already folded into h) ----------------
// tile: 128 rows x 128 cols-of-D. 4 waves, each 64x64.
__launch_bounds__(256)
__global__ void gemm2_kernel(const u16* __restrict__ hb, const u16* __restrict__ w2b,
                             const int* __restrict__ counts, const int* __restrict__ offsets,
                             const int* __restrict__ list,
                             float* __restrict__ out, int T, int D, int H) {
    int e = blockIdx.z, mblk = blockIdx.y, nblk = blockIdx.x;
    int count = counts[e];
    if (mblk * 128 >= count) return;

    __shared__ u16 sA[128 * LDA];
    __shared__ u16 sB[128 * LDA];

    int tid = threadIdx.x;
    int off0 = offsets[e];
    int n0 = nblk * 128;
    const u16* w2p = w2b + ((size_t)e * D + n0) * H;

    f32x4 acc[4][4];
#pragma unroll
    for (int mi = 0; mi < 4; mi++)
#pragma unroll
        for (int ni = 0; ni < 4; ni++) acc[mi][ni] = (f32x4)0.f;

    int lane = tid & 63, wvi = tid >> 6;
    int wm = (wvi & 1) * 64, wn = (wvi >> 1) * 64;
    int r = lane & 15, q = lane >> 4;

    for (int k0 = 0; k0 < H; k0 += 32) {
#pragma unroll
        for (int c = 0; c < 2; c++) {
            int idx = tid + c * 256;
            int row = idx >> 2;
            int col8 = (idx & 3) * 8;
            int rr = min(mblk * 128 + row, count - 1);   // clamp: stay inside this expert's rows
            *(uint4*)(&sA[row * LDA + col8]) =
                *(const uint4*)(hb + (size_t)(off0 + rr) * H + k0 + col8);
            *(uint4*)(&sB[row * LDA + col8]) =
                *(const uint4*)(w2p + (size_t)row * H + k0 + col8);
        }
        __syncthreads();

        short8 a[4], b[4];
#pragma unroll
        for (int mi = 0; mi < 4; mi++)
            a[mi] = *(const short8*)(&sA[(wm + mi * 16 + r) * LDA + q * 8]);
#pragma unroll
        for (int ni = 0; ni < 4; ni++)
            b[ni] = *(const short8*)(&sB[(wn + ni * 16 + r) * LDA + q * 8]);
#pragma unroll
        for (int mi = 0; mi < 4; mi++)
#pragma unroll
            for (int ni = 0; ni < 4; ni++)
                acc[mi][ni] = mfma16(a[mi], b[ni], acc[mi][ni]);
        __syncthreads();
    }

    // epilogue: scatter-add into out
#pragma unroll
    for (int mi = 0; mi < 4; mi++) {
#pragma unroll
        for (int tt = 0; tt < 4; tt++) {
            int rl = wm + mi * 16 + q * 4 + tt;
            int grow = mblk * 128 + rl;
            if (grow < count) {
                int tok = list[e * T + grow];
#pragma unroll
                for (int ni = 0; ni < 4; ni++) {
                    int col = n0 + wn + ni * 16 + r;
                    unsafeAtomicAdd(&out[(size_t)tok * D + col], acc[mi][ni][tt]);
                }
            }
        }
    }
}

extern "C" void kernel_launch(void* const* d_in, const int* in_sizes, int n_in,
                              void* d_out, int out_size, void* d_ws, size_t ws_size,
                              hipStream_t stream) {
    const float* x     = (const float*)d_in[0];
    const float* noise = (const float*)d_in[1];
    const float* rw    = (const float*)d_in[2];
    const float* rb    = (const float*)d_in[3];
    const float* nw    = (const float*)d_in[4];
    const float* nb    = (const float*)d_in[5];
    const float* w1    = (const float*)d_in[6];
    const float* w2    = (const float*)d_in[7];
    const float* w3    = (const float*)d_in[8];
    float* out = (float*)d_out;

    const int E = NE;
    const int D = in_sizes[2] / E;              // 1024
    const int T = in_sizes[0] / D;              // 8192
    const int H = in_sizes[6] / (E * D);        // 2048

    auto al = [](size_t v) { return (v + 255) & ~(size_t)255; };
    char* p = (char*)d_ws;
    size_t o_counts  = 0;                                     // 8 ints
    size_t o_offsets = 64;                                    // 9 ints
    size_t o_list    = 256;
    size_t o_glist   = al(o_list  + (size_t)E * T * 4);
    size_t o_xb      = al(o_glist + (size_t)E * T * 4);
    size_t o_w1b     = al(o_xb    + (size_t)T * D * 2);
    size_t o_w3b     = al(o_w1b   + (size_t)E * H * D * 2);
    size_t o_w2b     = al(o_w3b   + (size_t)E * H * D * 2);
    size_t o_hb      = al(o_w2b   + (size_t)E * D * H * 2);

    int*   counts  = (int*)(p + o_counts);
    int*   offsets = (int*)(p + o_offsets);
    int*   list    = (int*)(p + o_list);
    float* glist   = (float*)(p + o_glist);
    u16*   xb      = (u16*)(p + o_xb);
    u16*   w1b     = (u16*)(p + o_w1b);
    u16*   w3b     = (u16*)(p + o_w3b);
    u16*   w2b     = (u16*)(p + o_w2b);
    u16*   hb      = (u16*)(p + o_hb);

    hipMemsetAsync(counts, 0, 64, stream);
    hipMemsetAsync(out, 0, (size_t)T * D * 4, stream);

    // conversions
    cvt_kernel<<<2048, 256, 0, stream>>>(x,  xb,  (size_t)T * D / 4);
    cvt_kernel<<<2048, 256, 0, stream>>>(w1, w1b, (size_t)E * H * D / 4);
    cvt_kernel<<<2048, 256, 0, stream>>>(w3, w3b, (size_t)E * H * D / 4);
    cvt_kernel<<<2048, 256, 0, stream>>>(w2, w2b, (size_t)E * D * H / 4);

    // router + scan
    router_kernel<<<(T + 3) / 4, 256, 0, stream>>>(x, noise, rw, rb, nw, nb,
                                                   counts, list, glist, T, D);
    scan_kernel<<<1, 64, 0, stream>>>(counts, offsets);

    // expert GEMMs
    dim3 g1(H / 64, (T + 127) / 128, E);
    gemm1_kernel<<<g1, 256, 0, stream>>>(xb, w1b, w3b, counts, offsets, list, glist,
                                         hb, T, D, H);
    dim3 g2(D / 128, (T + 127) / 128, E);
    gemm2_kernel<<<g2, 256, 0, stream>>>(hb, w2b, counts, offsets, list,
                                         out, T, D, H);
}